// Round 9
// baseline (1100.368 us; speedup 1.0000x reference)
//
#include <hip/hip_runtime.h>

// ---------------- problem constants ----------------
#define NN      8192            // nodes
#define BB      32              // batch
#define EE      262144          // edges per support (2^18)
#define NB      (NN*BB)         // 262144 gemm rows
#define NS      2               // supports

// ---------------- workspace layout (byte offsets) ----------------
#define BOFF_OUTACC 0
#define BOFF_ZA     67108864
#define BOFF_ZB     100663296
#define BOFF_CSRVAL 134217728                    // f32  NS*EE
#define BOFF_CSRCOL (BOFF_CSRVAL + 2097152)      // int  NS*EE
#define BOFF_ROWPTR (BOFF_CSRCOL + 2097152)      // int  NS*(NN+1)
#define BOFF_CURSOR (BOFF_ROWPTR + 65544)        // int  NS*NN
#define BOFF_COUNTS (BOFF_CURSOR + 65536)        // int  NS*NN
// end ~132.2 MB

// ---------------- bf16 helpers (RNE) ----------------
__device__ __forceinline__ unsigned short f2bf(float f) {
    union { float f; unsigned u; } v; v.f = f;
    unsigned r = v.u + 0x7fffu + ((v.u >> 16) & 1u);
    return (unsigned short)(r >> 16);
}
__device__ __forceinline__ float bf_lo(unsigned u) {
    union { unsigned u; float f; } v; v.u = u << 16; return v.f;
}
__device__ __forceinline__ float bf_hi(unsigned u) {
    union { unsigned u; float f; } v; v.u = u & 0xffff0000u; return v.f;
}
__device__ __forceinline__ unsigned packbf(float lo, float hi) {
    return (unsigned)f2bf(lo) | ((unsigned)f2bf(hi) << 16);
}

typedef __bf16 bf16x8 __attribute__((ext_vector_type(8)));
typedef float  f32x4  __attribute__((ext_vector_type(4)));

// ---------------- CSR build ----------------
__global__ __launch_bounds__(256) void hist_kernel(const int* __restrict__ rows,
                                                   int* __restrict__ counts) {
    int idx = blockIdx.x * 256 + threadIdx.x;
    if (idx < NS * EE) {
        int s = idx >> 18;
        int r = rows[idx];
        atomicAdd(&counts[(s << 13) + r], 1);
    }
}

__global__ __launch_bounds__(1024) void scan_kernel(const int* __restrict__ counts,
                                                    int* __restrict__ row_ptr,
                                                    int* __restrict__ cursor) {
    const int s = blockIdx.x;
    const int tid = threadIdx.x;
    __shared__ int part[1024];
    int local[8];
    int sum = 0;
#pragma unroll
    for (int i = 0; i < 8; ++i) {
        local[i] = counts[(s << 13) + tid * 8 + i];
        sum += local[i];
    }
    part[tid] = sum;
    __syncthreads();
    for (int off = 1; off < 1024; off <<= 1) {
        int v = (tid >= off) ? part[tid - off] : 0;
        __syncthreads();
        part[tid] += v;
        __syncthreads();
    }
    int run = (tid == 0) ? 0 : part[tid - 1];
    const int base9 = s * (NN + 1);
    const int base8 = s << 13;
#pragma unroll
    for (int i = 0; i < 8; ++i) {
        row_ptr[base9 + tid * 8 + i] = run;
        cursor[base8 + tid * 8 + i] = run;
        run += local[i];
    }
    if (tid == 1023) row_ptr[base9 + NN] = run;   // == EE
}

__global__ __launch_bounds__(256) void scatter_kernel(const int* __restrict__ rows,
                                                      const int* __restrict__ cols,
                                                      const float* __restrict__ vals,
                                                      int* __restrict__ cursor,
                                                      int* __restrict__ csr_col,
                                                      float* __restrict__ csr_val) {
    int idx = blockIdx.x * 256 + threadIdx.x;
    if (idx < NS * EE) {
        int s = idx >> 18;
        int r = rows[idx];
        int p = atomicAdd(&cursor[(s << 13) + r], 1);
        csr_col[(s << 18) + p] = cols[idx];
        csr_val[(s << 18) + p] = vals[idx];
    }
}

// ---------------- dense GEMM via bf16 MFMA: Z_m = X0 @ W_m ----------------
// A[r = n*32+b][k] = k<64 ? inputs[b][n*64+k] : state[b][n*64+k-64]  (bf16)
// Block tile: 128 rows x 64 cols, K=128. 4 waves (2x2), wave tile 64x32.
// LDS holds A (swizzled [r][col8^(r&7)]) and W^T ([c][f], same swizzle).
// m==0 -> fp32 OUTACC ; m==1/3 -> bf16 za ; m==2/4 -> bf16 zb
__global__ __launch_bounds__(256) void gemm_mfma_kernel(const float* __restrict__ inputs,
                                                        const float* __restrict__ state,
                                                        const float* __restrict__ weight,
                                                        float* __restrict__ outacc,
                                                        unsigned short* __restrict__ za,
                                                        unsigned short* __restrict__ zb,
                                                        int mstart) {
    __shared__ unsigned short Abf[128 * 128];   // 32 KB, row r at r*128, 16B-group swizzle
    __shared__ unsigned short Wt[64 * 128];     // 16 KB, W^T: row c holds k=f contiguous
    const int tid = threadIdx.x;
    const int m = mstart + blockIdx.x;
    const int rowbase = blockIdx.y * 128;

    // ---- stage A: 2 threads per row (h = k-half of each 64-wide source) ----
    {
        const int r = tid >> 1, h = tid & 1;
        const int rg = rowbase + r, n = rg >> 5, b = rg & 31;
#pragma unroll
        for (int kt = 0; kt < 2; ++kt) {
            const float* srow = (kt ? state : inputs) + (size_t)b * (NN * 64) + n * 64 + h * 32;
            float f[32];
#pragma unroll
            for (int j = 0; j < 8; ++j) {
                float4 v = *(const float4*)(srow + j * 4);
                f[j * 4 + 0] = v.x; f[j * 4 + 1] = v.y;
                f[j * 4 + 2] = v.z; f[j * 4 + 3] = v.w;
            }
#pragma unroll
            for (int q = 0; q < 4; ++q) {
                int col8 = kt * 8 + h * 4 + q;          // k-group of 8
                uint4 pk;
                pk.x = packbf(f[q * 8 + 0], f[q * 8 + 1]);
                pk.y = packbf(f[q * 8 + 2], f[q * 8 + 3]);
                pk.z = packbf(f[q * 8 + 4], f[q * 8 + 5]);
                pk.w = packbf(f[q * 8 + 6], f[q * 8 + 7]);
                *(uint4*)&Abf[r * 128 + ((col8 ^ (r & 7)) * 8)] = pk;
            }
        }
    }
    // ---- stage W^T: lane c = tid&63, f-range g*32..+31 ----
    {
        const int c = tid & 63, g = tid >> 6;
        float wf[32];
#pragma unroll 8
        for (int i = 0; i < 32; ++i)
            wf[i] = weight[(size_t)((g * 32 + i) * 5 + m) * 64 + c];
#pragma unroll
        for (int q = 0; q < 4; ++q) {
            int col8 = g * 4 + q;
            uint4 pk;
            pk.x = packbf(wf[q * 8 + 0], wf[q * 8 + 1]);
            pk.y = packbf(wf[q * 8 + 2], wf[q * 8 + 3]);
            pk.z = packbf(wf[q * 8 + 4], wf[q * 8 + 5]);
            pk.w = packbf(wf[q * 8 + 6], wf[q * 8 + 7]);
            *(uint4*)&Wt[c * 128 + ((col8 ^ (c & 7)) * 8)] = pk;
        }
    }
    __syncthreads();

    // ---- MFMA main: wave (wid>>1) owns 64 rows, (wid&1) owns 32 cols ----
    const int lane = tid & 63;
    const int wid = tid >> 6;
    const int g = lane >> 4;            // k-group within fragment
    const int lr = lane & 15;
    f32x4 acc[4][2];
#pragma unroll
    for (int mi = 0; mi < 4; ++mi)
#pragma unroll
        for (int ni = 0; ni < 2; ++ni)
            acc[mi][ni] = (f32x4){0.f, 0.f, 0.f, 0.f};

#pragma unroll
    for (int ks = 0; ks < 4; ++ks) {            // K-steps of 32
        const int col8 = ks * 4 + g;
        bf16x8 afr[4], bfr[2];
#pragma unroll
        for (int mi = 0; mi < 4; ++mi) {
            int r = (wid >> 1) * 64 + mi * 16 + lr;
            afr[mi] = *(const bf16x8*)&Abf[r * 128 + ((col8 ^ (r & 7)) * 8)];
        }
#pragma unroll
        for (int ni = 0; ni < 2; ++ni) {
            int c = (wid & 1) * 32 + ni * 16 + lr;
            bfr[ni] = *(const bf16x8*)&Wt[c * 128 + ((col8 ^ (c & 7)) * 8)];
        }
#pragma unroll
        for (int mi = 0; mi < 4; ++mi)
#pragma unroll
            for (int ni = 0; ni < 2; ++ni)
                acc[mi][ni] = __builtin_amdgcn_mfma_f32_16x16x32_bf16(
                    afr[mi], bfr[ni], acc[mi][ni], 0, 0, 0);
    }

    // ---- epilogue: D[row=(lane>>4)*4+i][col=lane&15] (HW-verified mapping) ----
    const int i0 = (lane >> 4) * 4;
#pragma unroll
    for (int mi = 0; mi < 4; ++mi) {
#pragma unroll
        for (int ni = 0; ni < 2; ++ni) {
#pragma unroll
            for (int i = 0; i < 4; ++i) {
                int row = rowbase + (wid >> 1) * 64 + mi * 16 + i0 + i;
                int col = (wid & 1) * 32 + ni * 16 + lr;
                int n = row >> 5, b = row & 31;
                float v = acc[mi][ni][i];
                if (m == 0) {
                    outacc[(size_t)n * 2048 + b * 64 + col] = v;
                } else {
                    unsigned short* dst = (m == 1 || m == 3) ? za : zb;
                    dst[(size_t)n * 2048 + b * 64 + col] = f2bf(v);
                }
            }
        }
    }
}

// ---------------- SpMM U: V = Z_a + 2*(A @ Z_b), in place into za ----------
__global__ __launch_bounds__(256) void spmmU_kernel(const int* __restrict__ row_ptr,
                                                    const int* __restrict__ csr_col,
                                                    const float* __restrict__ csr_val,
                                                    unsigned short* __restrict__ za,
                                                    const unsigned short* __restrict__ zb,
                                                    int s) {
    const int r = blockIdx.x;
    const int tid = threadIdx.x;
    const int e0 = row_ptr[s * (NN + 1) + r];
    const int e1 = row_ptr[s * (NN + 1) + r + 1];
    const int* cc = csr_col + (s << 18);
    const float* cv = csr_val + (s << 18);
    const uint4* zbq = (const uint4*)zb;
    float acc[8];
#pragma unroll
    for (int i = 0; i < 8; ++i) acc[i] = 0.f;
    for (int e = e0; e < e1; ++e) {
        int c = cc[e];
        float v = cv[e];
        uint4 x = zbq[(size_t)c * 256 + tid];
        acc[0] += v * bf_lo(x.x); acc[1] += v * bf_hi(x.x);
        acc[2] += v * bf_lo(x.y); acc[3] += v * bf_hi(x.y);
        acc[4] += v * bf_lo(x.z); acc[5] += v * bf_hi(x.z);
        acc[6] += v * bf_lo(x.w); acc[7] += v * bf_hi(x.w);
    }
    uint4* zaq = (uint4*)za;
    uint4 a = zaq[(size_t)r * 256 + tid];
    uint4 outv;
    outv.x = packbf(bf_lo(a.x) + 2.f * acc[0], bf_hi(a.x) + 2.f * acc[1]);
    outv.y = packbf(bf_lo(a.y) + 2.f * acc[2], bf_hi(a.y) + 2.f * acc[3]);
    outv.z = packbf(bf_lo(a.z) + 2.f * acc[4], bf_hi(a.z) + 2.f * acc[5]);
    outv.w = packbf(bf_lo(a.w) + 2.f * acc[6], bf_hi(a.w) + 2.f * acc[7]);
    zaq[(size_t)r * 256 + tid] = outv;
}

// ---------------- SpMM V: OUTACC += (A @ V) - Z_b ------------------------
__global__ __launch_bounds__(256) void spmmV_kernel(const int* __restrict__ row_ptr,
                                                    const int* __restrict__ csr_col,
                                                    const float* __restrict__ csr_val,
                                                    const unsigned short* __restrict__ vbuf,
                                                    const unsigned short* __restrict__ zb,
                                                    float* __restrict__ outacc,
                                                    int s) {
    const int r = blockIdx.x;
    const int tid = threadIdx.x;
    const int e0 = row_ptr[s * (NN + 1) + r];
    const int e1 = row_ptr[s * (NN + 1) + r + 1];
    const int* cc = csr_col + (s << 18);
    const float* cv = csr_val + (s << 18);
    const uint4* vq = (const uint4*)vbuf;
    float acc[8];
#pragma unroll
    for (int i = 0; i < 8; ++i) acc[i] = 0.f;
    for (int e = e0; e < e1; ++e) {
        int c = cc[e];
        float v = cv[e];
        uint4 x = vq[(size_t)c * 256 + tid];
        acc[0] += v * bf_lo(x.x); acc[1] += v * bf_hi(x.x);
        acc[2] += v * bf_lo(x.y); acc[3] += v * bf_hi(x.y);
        acc[4] += v * bf_lo(x.z); acc[5] += v * bf_hi(x.z);
        acc[6] += v * bf_lo(x.w); acc[7] += v * bf_hi(x.w);
    }
    uint4 t = ((const uint4*)zb)[(size_t)r * 256 + tid];
    float* p = outacc + (size_t)r * 2048 + tid * 8;
    float4 o0 = *(float4*)p, o1 = *(float4*)(p + 4);
    o0.x += acc[0] - bf_lo(t.x); o0.y += acc[1] - bf_hi(t.x);
    o0.z += acc[2] - bf_lo(t.y); o0.w += acc[3] - bf_hi(t.y);
    o1.x += acc[4] - bf_lo(t.z); o1.y += acc[5] - bf_hi(t.z);
    o1.z += acc[6] - bf_lo(t.w); o1.w += acc[7] - bf_hi(t.w);
    *(float4*)p = o0; *(float4*)(p + 4) = o1;
}

// ---------------- epilogue: out[b][n*64+o] = OUTACC[n][b][o] + bias[o] ----
__global__ __launch_bounds__(256) void bias_kernel(const float* __restrict__ outacc,
                                                   const float* __restrict__ biases,
                                                   float* __restrict__ out) {
    const int b = blockIdx.y;
    const int n = blockIdx.x * 16 + (threadIdx.x >> 4);
    const int o = (threadIdx.x & 15) * 4;
    float4 v = *(const float4*)(outacc + (size_t)n * 2048 + b * 64 + o);
    float4 bi = *(const float4*)(biases + o);
    v.x += bi.x; v.y += bi.y; v.z += bi.z; v.w += bi.w;
    *(float4*)(out + (size_t)b * (NN * 64) + n * 64 + o) = v;
}

// ---------------- host ----------------
extern "C" void kernel_launch(void* const* d_in, const int* in_sizes, int n_in,
                              void* d_out, int out_size, void* d_ws, size_t ws_size,
                              hipStream_t stream) {
    const float* inputs = (const float*)d_in[0];
    const float* state  = (const float*)d_in[1];
    const int*   rows   = (const int*)d_in[2];
    const int*   cols   = (const int*)d_in[3];
    const float* vals   = (const float*)d_in[4];
    const float* weight = (const float*)d_in[5];
    const float* biases = (const float*)d_in[6];
    float* out = (float*)d_out;

    char* base = (char*)d_ws;
    float*          outacc  = (float*)(base + BOFF_OUTACC);
    unsigned short* za      = (unsigned short*)(base + BOFF_ZA);
    unsigned short* zb      = (unsigned short*)(base + BOFF_ZB);
    float*          csr_val = (float*)(base + BOFF_CSRVAL);
    int*            csr_col = (int*)(base + BOFF_CSRCOL);
    int*            row_ptr = (int*)(base + BOFF_ROWPTR);
    int*            cursor  = (int*)(base + BOFF_CURSOR);
    int*            counts  = (int*)(base + BOFF_COUNTS);

    // CSR build (both supports)
    hipMemsetAsync(counts, 0, NS * NN * sizeof(int), stream);
    hist_kernel<<<(NS * EE + 255) / 256, 256, 0, stream>>>(rows, counts);
    scan_kernel<<<NS, 1024, 0, stream>>>(counts, row_ptr, cursor);
    scatter_kernel<<<(NS * EE + 255) / 256, 256, 0, stream>>>(rows, cols, vals, cursor,
                                                              csr_col, csr_val);

    for (int s = 0; s < NS; ++s) {
        int mstart = (s == 0) ? 0 : 3;
        int mcount = (s == 0) ? 3 : 2;   // s=0 also produces the m=0 (identity) term
        gemm_mfma_kernel<<<dim3(mcount, NB / 128), 256, 0, stream>>>(inputs, state, weight,
                                                                     outacc, za, zb, mstart);
        spmmU_kernel<<<NN, 256, 0, stream>>>(row_ptr, csr_col, csr_val, za, zb, s);
        spmmV_kernel<<<NN, 256, 0, stream>>>(row_ptr, csr_col, csr_val, za, zb,
                                             outacc, s);
    }

    bias_kernel<<<dim3(NN / 16, BB), 256, 0, stream>>>(outacc, biases, out);
}